// Round 10
// baseline (224.074 us; speedup 1.0000x reference)
//
#include <hip/hip_runtime.h>
#include <cstdint>
#include <cstddef>

#define BATCH   16384
#define N_IN    128
#define CTX     128
#define HDIM    1024
#define NB      8
#define OUT_MULT 23                 // 3*NB-1 (logical)
#define OUT_PAD 24                  // padded per-group width (col 23 = zeros)
#define NOUTP   (N_IN * OUT_PAD)    // 3072
#define KCAT    (CTX + N_IN)        // 256

typedef __bf16 bf16x8 __attribute__((ext_vector_type(8)));
typedef float  f32x4  __attribute__((ext_vector_type(4)));

__device__ __forceinline__ uint16_t f2bf(float f) {
    union { float f; uint32_t u; } v; v.f = f;
    uint32_t u = v.u;
    u += 0x7FFFu + ((u >> 16) & 1u);   // RNE
    return (uint16_t)(u >> 16);
}

// ---- degree-sorted permutation of the hidden dim ---------------------------
// deg(h) = h % 127; stable sort by deg. count(d) = 9 for d<8, 8 for d>=8.
// kpref(d) = #{h : deg(h) < d}; position p -> (d, occurrence j) -> h = d+127*j
__device__ __forceinline__ int kpref_dev(int d) {
    return (d <= 8) ? 9 * d : 72 + 8 * (d - 8);
}
__device__ __forceinline__ int dpos_dev(int p) {
    return (p < 72) ? (p / 9) : (8 + ((p - 72) >> 3));
}
__device__ __forceinline__ int h_of(int p) {
    if (p < 72) { int d = p / 9, j = p - 9 * d; return d + 127 * j; }
    int q = p - 72; int d = 8 + (q >> 3); int j = q & 7; return d + 127 * j;
}

// async global->LDS, 16B per lane; LDS dest = wave-uniform base + lane*16,
// global side is a per-lane address (gather is allowed).
__device__ __forceinline__ void async_ld16(const void* g, const void* l) {
    __builtin_amdgcn_global_load_lds(
        (__attribute__((address_space(1))) void*)(uintptr_t)g,
        (__attribute__((address_space(3))) void*)(uint32_t)(uintptr_t)l,
        16, 0, 0);
}

// ---------------- one fused pack kernel (coalesced; verified R9) ------------
// block ranges: [0,4096) xcat | [4096,5120) wcat | [5120,6144) w1m
//               [6144,9216) w2p | [9216,9232) biases | [9232,9296) ld=0

__global__ void pack_all(
    const float* __restrict__ x,    const float* __restrict__ ctx,
    const float* __restrict__ ctx_w,const float* __restrict__ w0,
    const float* __restrict__ b0,   const float* __restrict__ w1,
    const float* __restrict__ b1,   const float* __restrict__ w2,
    const float* __restrict__ b2,
    uint16_t* __restrict__ xcat, uint16_t* __restrict__ wcat,
    uint16_t* __restrict__ w1m,  uint16_t* __restrict__ w2p,
    float* __restrict__ b0p, float* __restrict__ b1p, float* __restrict__ b2p,
    float* __restrict__ ldz)
{
    __shared__ float srow[HDIM];             // 4 KB staging for permuted packs
    const int blk = blockIdx.x;
    const int tid = threadIdx.x;

    if (blk < 4096) {                        // xcat: BATCH x KCAT, 4 elem/thread
        int idx4 = (blk * 256 + tid) * 4;
        int b = idx4 >> 8, c = idx4 & 255;
        f32x4 v = (c < CTX) ? *(const f32x4*)(ctx + (b << 7) + c)
                            : *(const f32x4*)(x   + (b << 7) + (c - CTX));
        ushort4 o;
        o.x = f2bf(v[0]); o.y = f2bf(v[1]); o.z = f2bf(v[2]); o.w = f2bf(v[3]);
        *(ushort4*)(xcat + idx4) = o;
    } else if (blk < 5120) {                 // wcat: HDIM x KCAT, rows sorted
        int idx = (blk - 4096) * 256 + tid;
        int p = idx >> 8, c = idx & 255;
        int h = h_of(p);
        float v;
        if (c < CTX) v = ctx_w[(h << 7) + c];
        else {
            int col = c - CTX;               // mask0: dpos(p) >= col
            v = (dpos_dev(p) >= col) ? w0[(h << 7) + col] : 0.0f;
        }
        wcat[idx] = f2bf(v);
    } else if (blk < 6144) {                 // w1m: one dest row per block
        const int po = blk - 5120;
        const int drow = dpos_dev(po);
        const float* src = w1 + (size_t)h_of(po) * HDIM;
        *((f32x4*)srow + tid) = *((const f32x4*)src + tid);   // 1024 floats
        __syncthreads();
        ushort4 o;
#pragma unroll
        for (int e = 0; e < 4; ++e) {
            int pi = 4 * tid + e;
            float v = (drow >= dpos_dev(pi)) ? srow[h_of(pi)] : 0.0f;
            ((uint16_t*)&o)[e] = f2bf(v);
        }
        *((ushort4*)(w1m + (size_t)po * HDIM) + tid) = o;
    } else if (blk < 9216) {                 // w2p: one dest row per block
        const int oo = blk - 6144;           // 0..3071
        const int g = oo / OUT_PAD, t = oo - g * OUT_PAD;
        const bool live = (t < OUT_MULT);    // block-uniform branch
        if (live) {
            const float* src = w2 + (size_t)(g * OUT_MULT + t) * HDIM;
            *((f32x4*)srow + tid) = *((const f32x4*)src + tid);
        }
        __syncthreads();
        ushort4 o;
#pragma unroll
        for (int e = 0; e < 4; ++e) {
            int pi = 4 * tid + e;
            float v = (live && g > dpos_dev(pi)) ? srow[h_of(pi)] : 0.0f;
            ((uint16_t*)&o)[e] = f2bf(v);
        }
        *((ushort4*)(w2p + (size_t)oo * HDIM) + tid) = o;
    } else if (blk < 9232) {                 // biases
        int idx = (blk - 9216) * 256 + tid;  // 0..4095
        if (idx < HDIM) {
            int h = h_of(idx);
            b0p[idx] = b0[h];
            b1p[idx] = b1[h];
        } else {
            int oo = idx - HDIM;             // 0..3071
            int g = oo / OUT_PAD, t = oo - g * OUT_PAD;
            b2p[oo] = (t < OUT_MULT) ? b2[g * OUT_MULT + t] : 0.0f;
        }
    } else {                                 // zero ldsum (BATCH floats)
        int idx = (blk - 9232) * 256 + tid;
        ldz[idx] = 0.0f;
    }
}

// ---------------- bf16 GEMM, C = A(MxK) @ B(NxK)^T + bias (relu, bf16 out) --
// BK=64, XOR-swizzled LDS (conflict-free ds_read_b128), K prefix by MODE.

template<int MODE>
__global__ __launch_bounds__(256, 2) void gemm_bt(
    const uint16_t* __restrict__ A,
    const uint16_t* __restrict__ B,
    const float*    __restrict__ bias,
    uint16_t*       __restrict__ C,
    int N, int K, int NT)
{
    __shared__ __align__(16) uint16_t sA[128 * 64];   // 16 KB
    __shared__ __align__(16) uint16_t sB[128 * 64];   // 16 KB

    const int GM    = 64;
    const int per   = GM * NT;
    const int id    = blockIdx.x;
    const int grp   = id / per;
    const int rem   = id - grp * per;
    const int mt    = grp * GM + (rem & (GM - 1));
    const int nt    = rem >> 6;
    const int bm    = mt << 7;
    const int bn    = nt << 7;

    int K_eff;
    if (MODE == 0)      { int dmax = dpos_dev(bn + 127); K_eff = 128 + dmax + 1; }
    else                { int dmax = dpos_dev(bn + 127); K_eff = kpref_dev(dmax + 1); }
    K_eff = min(K, (K_eff + 63) & ~63);

    const int tid   = threadIdx.x;
    const int wid   = tid >> 6;
    const int lane  = tid & 63;
    const int wm    = (wid & 1) << 6;
    const int wn    = (wid >> 1) << 6;
    const int lrow  = lane & 15;
    const int lquad = lane >> 4;

    const f32x4 vzero = {0.0f, 0.0f, 0.0f, 0.0f};
    f32x4 acc[4][4];
#pragma unroll
    for (int i = 0; i < 4; ++i)
#pragma unroll
        for (int j = 0; j < 4; ++j) acc[i][j] = vzero;

    int goff[4];
#pragma unroll
    for (int t = 0; t < 4; ++t) {
        int c = t * 256 + tid;
        int row = c >> 3, j = c & 7;
        int oct = j ^ (row & 7);
        goff[t] = row * K * 2 + oct * 16;    // bytes
    }
    const char* gA = (const char*)(A + (size_t)bm * K);
    const char* gB = (const char*)(B + (size_t)bn * K);

    const int octx = lrow & 7;
    const uint16_t* rA = sA + (wm + lrow) * 64;
    const uint16_t* rB = sB + (wn + lrow) * 64;

    for (int k0 = 0; k0 < K_eff; k0 += 64) {
        __syncthreads();
        const int kb = k0 * 2;
#pragma unroll
        for (int t = 0; t < 4; ++t) {
            const int ldsoff = (t * 256 + (wid << 6)) * 16;   // wave-uniform
            async_ld16(gA + goff[t] + kb, (const char*)sA + ldsoff);
            async_ld16(gB + goff[t] + kb, (const char*)sB + ldsoff);
        }
        __syncthreads();

#pragma unroll
        for (int ks = 0; ks < 2; ++ks) {
            const int oct = ((ks << 2) | lquad) ^ octx;
            bf16x8 af[4], bfr[4];
#pragma unroll
            for (int i = 0; i < 4; ++i) af[i]  = *(const bf16x8*)(rA + i * 1024 + oct * 8);
#pragma unroll
            for (int j = 0; j < 4; ++j) bfr[j] = *(const bf16x8*)(rB + j * 1024 + oct * 8);
#pragma unroll
            for (int i = 0; i < 4; ++i)
#pragma unroll
                for (int j = 0; j < 4; ++j)
                    acc[i][j] = __builtin_amdgcn_mfma_f32_16x16x32_bf16(
                                    af[i], bfr[j], acc[i][j], 0, 0, 0);
        }
    }

#pragma unroll
    for (int j = 0; j < 4; ++j) {
        const int col = bn + wn + j * 16 + lrow;
        const float bv = bias[col];
#pragma unroll
        for (int i = 0; i < 4; ++i) {
            const int row0 = bm + wm + i * 16 + (lquad << 2);
#pragma unroll
            for (int r = 0; r < 4; ++r) {
                float v = fmaxf(acc[i][j][r] + bv, 0.0f);
                C[(size_t)(row0 + r) * N + col] = f2bf(v);
            }
        }
    }
}

// ---------------- spline evaluation (VERBATIM known-good math) --------------
// NOTE: the trans-op diet (Taylor softmax exp + fused log) failed absmax=0.75
// in R7/R8 despite airtight algebra -- unresolved. Do NOT touch this math.

__device__ __forceinline__ float frcp(float v) { return __builtin_amdgcn_rcpf(v); }
__device__ __forceinline__ float softplusf(float v) {
    return fmaxf(v, 0.0f) + __logf(1.0f + __expf(-fabsf(v)));
}

__device__ __forceinline__ void spline_eval(const float* __restrict__ pp,
                                            float xv, float& yout, float& ldout)
{
    float p[OUT_MULT];
#pragma unroll
    for (int k = 0; k < OUT_MULT; ++k) p[k] = pp[k];

    const float TAILF = 3.0f;
    const float MIN_W = 0.001f, MIN_H = 0.001f, MIN_D = 0.001f;
    const float INV_SCALE = 1.0f / 724.0773439350246f;   // 1/sqrt(H*H/2)

    const float xc = fminf(fmaxf(xv, -TAILF), TAILF);

    float uw[NB], uh[NB];
#pragma unroll
    for (int k = 0; k < NB; ++k) { uw[k] = p[k] * INV_SCALE; uh[k] = p[NB + k] * INV_SCALE; }
    float mw = uw[0], mh = uh[0];
#pragma unroll
    for (int k = 1; k < NB; ++k) { mw = fmaxf(mw, uw[k]); mh = fmaxf(mh, uh[k]); }
    float ew[NB], eh[NB], sw = 0.0f, sh = 0.0f;
#pragma unroll
    for (int k = 0; k < NB; ++k) {
        ew[k] = __expf(uw[k] - mw); sw += ew[k];
        eh[k] = __expf(uh[k] - mh); sh += eh[k];
    }
    const float FACW = (1.0f - MIN_W * NB) * frcp(sw);
    const float FACH = (1.0f - MIN_H * NB) * frcp(sh);

    float cw[NB + 1], ch[NB + 1];
    cw[0] = -TAILF; ch[0] = -TAILF;
    float aw = 0.0f, ah = 0.0f;
#pragma unroll
    for (int k = 0; k < NB; ++k) {
        aw += MIN_W + FACW * ew[k];
        ah += MIN_H + FACH * eh[k];
        cw[k + 1] = (k == NB - 1) ? TAILF : 2.0f * TAILF * aw - TAILF;
        ch[k + 1] = (k == NB - 1) ? TAILF : 2.0f * TAILF * ah - TAILF;
    }

    float dd[NB + 1];
    dd[0]  = 1.0f;   // MIN_D + softplus(DPAD) == 1 exactly by construction
    dd[NB] = 1.0f;
#pragma unroll
    for (int k = 1; k < NB; ++k) dd[k] = MIN_D + softplusf(p[2 * NB + (k - 1)]);

    float in_cw = cw[0], cw_n = cw[1], in_ch = ch[0], ch_n = ch[1];
    float d0 = dd[0], d1 = dd[1];
#pragma unroll
    for (int k = 1; k < NB; ++k) {
        const bool ge = (xc >= cw[k]);
        in_cw = ge ? cw[k]     : in_cw;
        cw_n  = ge ? cw[k + 1] : cw_n;
        in_ch = ge ? ch[k]     : in_ch;
        ch_n  = ge ? ch[k + 1] : ch_n;
        d0    = ge ? dd[k]     : d0;
        d1    = ge ? dd[k + 1] : d1;
    }
    const float in_w  = cw_n - in_cw;
    const float in_h  = ch_n - in_ch;
    const float inv_w = frcp(in_w);
    const float delta = in_h * inv_w;
    const float theta = (xc - in_cw) * inv_w;
    const float omt   = 1.0f - theta;
    const float t1m   = theta * omt;
    const float denom = delta + (d0 + d1 - 2.0f * delta) * t1m;
    const float num   = in_h * (delta * theta * theta + d0 * t1m);
    float yv = in_ch + num * frcp(denom);
    float ld = 2.0f * __logf(delta)
             + __logf(d1 * theta * theta + 2.0f * delta * t1m + d0 * omt * omt)
             - 2.0f * __logf(denom);
    const bool inside = fabsf(xv) <= TAILF;
    yout  = inside ? yv : xv;
    ldout = inside ? ld : 0.0f;
}

// ---------------- fused GEMM3 + spline --------------------------------------
// Block tile: 128 M x 96 N (= 4 complete padded groups). Waves 2x2: 64 x 48.
// BK=64 + XOR-swizzled LDS. K prefix: kpref(4*nt+3) rounded to 64
// (zero-weight tail -> bit-identical).
// SINGLE-phase epilogue: full 128 x stride-100 f32 ep tile (51.2 KB, aliases
// dead staging; 3 blocks/CU unchanged). stride 100: quad store offset
// 400%32=16 -> every bank exactly 2x -> conflict-free writes; row*100+sg*24
// is 16B-aligned -> spline p-loads mergeable into ds_read_b128.

__global__ __launch_bounds__(256, 2) void gemm3_spline(
    const uint16_t* __restrict__ A,      // h2: BATCH x HDIM (sorted K)
    const uint16_t* __restrict__ B,      // w2p: NOUTP x HDIM
    const float*    __restrict__ bias,   // b2p: NOUTP
    const float*    __restrict__ x,      // BATCH x N_IN
    float* __restrict__ y,
    float* __restrict__ ldsum)
{
    __shared__ __align__(16) char smem[128 * 100 * 4];   // 51200 B
    uint16_t* sA = (uint16_t*)smem;                 // 128*64*2 = 16384
    uint16_t* sB = (uint16_t*)(smem + 16384);       //  96*64*2 = 12288
    float* ep    = (float*)smem;                    // 128*100*4 (alias, full)

    const int NT  = 32;
    const int per = 64 * NT;                        // 2048
    const int id  = blockIdx.x;
    const int grp = id / per;
    const int rem = id - grp * per;
    const int mt  = grp * 64 + (rem & 63);
    const int nt  = rem >> 6;
    const int bm  = mt << 7;
    const int bn  = nt * 96;

    const int K = HDIM;
    int K_eff = kpref_dev(4 * nt + 3);
    K_eff = min(K, (K_eff + 63) & ~63);

    const int tid   = threadIdx.x;
    const int wid   = tid >> 6;
    const int lane  = tid & 63;
    const int wm    = (wid & 1) << 6;
    const int wn    = (wid >> 1) * 48;
    const int lrow  = lane & 15;
    const int lquad = lane >> 4;

    const f32x4 vzero = {0.0f, 0.0f, 0.0f, 0.0f};
    f32x4 acc[4][3];
#pragma unroll
    for (int i = 0; i < 4; ++i)
#pragma unroll
        for (int j = 0; j < 3; ++j) acc[i][j] = vzero;

    int goffA[4], goffB[3];
#pragma unroll
    for (int t = 0; t < 4; ++t) {
        int c = t * 256 + tid;
        int row = c >> 3, j = c & 7;
        goffA[t] = row * K * 2 + (j ^ (row & 7)) * 16;
    }
#pragma unroll
    for (int t = 0; t < 3; ++t) {
        int c = t * 256 + tid;
        int row = c >> 3, j = c & 7;
        goffB[t] = row * K * 2 + (j ^ (row & 7)) * 16;
    }
    const char* gA = (const char*)(A + (size_t)bm * K);
    const char* gB = (const char*)(B + (size_t)bn * K);

    const int octx = lrow & 7;
    const uint16_t* rA = sA + (wm + lrow) * 64;
    const uint16_t* rB = sB + (wn + lrow) * 64;

    for (int k0 = 0; k0 < K_eff; k0 += 64) {
        __syncthreads();
        const int kb = k0 * 2;
#pragma unroll
        for (int t = 0; t < 4; ++t) {
            const int ldsoff = (t * 256 + (wid << 6)) * 16;
            async_ld16(gA + goffA[t] + kb, (const char*)sA + ldsoff);
            if (t < 3)
                async_ld16(gB + goffB[t] + kb, (const char*)sB + ldsoff);
        }
        __syncthreads();

#pragma unroll
        for (int ks = 0; ks < 2; ++ks) {
            const int oct = ((ks << 2) | lquad) ^ octx;
            bf16x8 af[4], bfr[3];
#pragma unroll
            for (int i = 0; i < 4; ++i) af[i]  = *(const bf16x8*)(rA + i * 1024 + oct * 8);
#pragma unroll
            for (int j = 0; j < 3; ++j) bfr[j] = *(const bf16x8*)(rB + j * 1024 + oct * 8);
#pragma unroll
            for (int i = 0; i < 4; ++i)
#pragma unroll
                for (int j = 0; j < 3; ++j)
                    acc[i][j] = __builtin_amdgcn_mfma_f32_16x16x32_bf16(
                                    af[i], bfr[j], acc[i][j], 0, 0, 0);
        }
    }

    __syncthreads();                    // staging consumers done; reuse as ep
#pragma unroll
    for (int j = 0; j < 3; ++j) {
        const int col = wn + j * 16 + lrow;
        const float bv = bias[bn + col];
#pragma unroll
        for (int i = 0; i < 4; ++i) {
            const int r0 = wm + i * 16 + (lquad << 2);
#pragma unroll
            for (int r = 0; r < 4; ++r)
                ep[(r0 + r) * 100 + col] = acc[i][j][r] + bv;
        }
    }
    __syncthreads();

    // 512 spline evals: thread handles elements tid and tid+256
#pragma unroll
    for (int e = 0; e < 2; ++e) {
        const int idx  = tid + (e << 8);
        const int row  = idx >> 2;          // 0..127
        const int sg   = idx & 3;           // group within tile
        const int grow = bm + row;
        const float xv = x[(size_t)grow * N_IN + (4 * nt + sg)];
        float yv, ld;
        spline_eval(ep + row * 100 + sg * OUT_PAD, xv, yv, ld);
        y[(size_t)grow * N_IN + 4 * nt + sg] = yv;

        // sum ld over the 4 lanes of the quad (same row)
        ld += __shfl_xor(ld, 1, 64);
        ld += __shfl_xor(ld, 2, 64);
        if (sg == 0) atomicAdd(&ldsum[grow], ld);
    }
}

// ---------------- host orchestration ----------------------------------------

extern "C" void kernel_launch(void* const* d_in, const int* in_sizes, int n_in,
                              void* d_out, int out_size, void* d_ws, size_t ws_size,
                              hipStream_t stream)
{
    const float* x     = (const float*)d_in[0];
    const float* ctx   = (const float*)d_in[1];
    const float* ctx_w = (const float*)d_in[2];
    const float* w0    = (const float*)d_in[3];
    const float* b0    = (const float*)d_in[4];
    const float* w1    = (const float*)d_in[5];
    const float* b1    = (const float*)d_in[6];
    const float* w2    = (const float*)d_in[7];
    const float* b2    = (const float*)d_in[8];
    // d_in[9..11] = masks: unused (computed analytically from indices)

    char* ws = (char*)d_ws;
    const size_t XCAT_B = (size_t)BATCH * KCAT * 2;   //   8 MB
    const size_t H_B    = (size_t)BATCH * HDIM * 2;   //  32 MB each
    const size_t WCAT_B = (size_t)HDIM * KCAT * 2;
    const size_t W1_B   = (size_t)HDIM * HDIM * 2;
    const size_t W2P_B  = (size_t)NOUTP * HDIM * 2;

    uint16_t* xcat = (uint16_t*)(ws);
    uint16_t* h1   = (uint16_t*)(ws + XCAT_B);
    uint16_t* h2   = (uint16_t*)(ws + XCAT_B + H_B);
    uint16_t* wcat = (uint16_t*)(ws + XCAT_B + 2 * H_B);
    uint16_t* w1m  = (uint16_t*)(ws + XCAT_B + 2 * H_B + WCAT_B);
    uint16_t* w2p  = (uint16_t*)(ws + XCAT_B + 2 * H_B + WCAT_B + W1_B);
    float*    b0p  = (float*)   (ws + XCAT_B + 2 * H_B + WCAT_B + W1_B + W2P_B);
    float*    b1p  = b0p + HDIM;
    float*    b2p  = b1p + HDIM;

    float* yout  = (float*)d_out;
    float* ldout = yout + (size_t)BATCH * N_IN;

    pack_all<<<9296, 256, 0, stream>>>(x, ctx, ctx_w, w0, b0, w1, b1, w2, b2,
                                       xcat, wcat, w1m, w2p, b0p, b1p, b2p,
                                       ldout);

    const dim3 blk(256);
    gemm_bt<0><<<dim3(128 * (HDIM / 128)), blk, 0, stream>>>(
        xcat, wcat, b0p, h1, HDIM, KCAT, HDIM / 128);
    gemm_bt<1><<<dim3(128 * (HDIM / 128)), blk, 0, stream>>>(
        h1, w1m, b1p, h2, HDIM, HDIM, HDIM / 128);
    gemm3_spline<<<dim3(128 * 32), blk, 0, stream>>>(
        h2, w2p, b2p, x, yout, ldout);
}

// Round 11
// 214.843 us; speedup vs baseline: 1.0430x; 1.0430x over previous
//
#include <hip/hip_runtime.h>
#include <cstdint>
#include <cstddef>

#define BATCH   16384
#define N_IN    128
#define CTX     128
#define HDIM    1024
#define NB      8
#define OUT_MULT 23                 // 3*NB-1 (logical)
#define OUT_PAD 24                  // padded per-group width (col 23 = zeros)
#define NOUTP   (N_IN * OUT_PAD)    // 3072
#define KCAT    (CTX + N_IN)        // 256

typedef __bf16 bf16x8 __attribute__((ext_vector_type(8)));
typedef float  f32x4  __attribute__((ext_vector_type(4)));

__device__ __forceinline__ uint16_t f2bf(float f) {
    union { float f; uint32_t u; } v; v.f = f;
    uint32_t u = v.u;
    u += 0x7FFFu + ((u >> 16) & 1u);   // RNE
    return (uint16_t)(u >> 16);
}

// ---- degree-sorted permutation of the hidden dim ---------------------------
// deg(h) = h % 127; stable sort by deg. count(d) = 9 for d<8, 8 for d>=8.
// kpref(d) = #{h : deg(h) < d}; position p -> (d, occurrence j) -> h = d+127*j
__device__ __forceinline__ int kpref_dev(int d) {
    return (d <= 8) ? 9 * d : 72 + 8 * (d - 8);
}
__device__ __forceinline__ int dpos_dev(int p) {
    return (p < 72) ? (p / 9) : (8 + ((p - 72) >> 3));
}
__device__ __forceinline__ int h_of(int p) {
    if (p < 72) { int d = p / 9, j = p - 9 * d; return d + 127 * j; }
    int q = p - 72; int d = 8 + (q >> 3); int j = q & 7; return d + 127 * j;
}

// async global->LDS, 16B per lane; LDS dest = wave-uniform base + lane*16,
// global side is a per-lane address (gather is allowed).
__device__ __forceinline__ void async_ld16(const void* g, const void* l) {
    __builtin_amdgcn_global_load_lds(
        (__attribute__((address_space(1))) void*)(uintptr_t)g,
        (__attribute__((address_space(3))) void*)(uint32_t)(uintptr_t)l,
        16, 0, 0);
}

// ---------------- one fused pack kernel (coalesced; verified R9) ------------
// block ranges: [0,4096) xcat | [4096,5120) wcat | [5120,6144) w1m
//               [6144,9216) w2p | [9216,9232) biases | [9232,9296) ld=0

__global__ void pack_all(
    const float* __restrict__ x,    const float* __restrict__ ctx,
    const float* __restrict__ ctx_w,const float* __restrict__ w0,
    const float* __restrict__ b0,   const float* __restrict__ w1,
    const float* __restrict__ b1,   const float* __restrict__ w2,
    const float* __restrict__ b2,
    uint16_t* __restrict__ xcat, uint16_t* __restrict__ wcat,
    uint16_t* __restrict__ w1m,  uint16_t* __restrict__ w2p,
    float* __restrict__ b0p, float* __restrict__ b1p, float* __restrict__ b2p,
    float* __restrict__ ldz)
{
    __shared__ float srow[HDIM];             // 4 KB staging for permuted packs
    const int blk = blockIdx.x;
    const int tid = threadIdx.x;

    if (blk < 4096) {                        // xcat: BATCH x KCAT, 4 elem/thread
        int idx4 = (blk * 256 + tid) * 4;
        int b = idx4 >> 8, c = idx4 & 255;
        f32x4 v = (c < CTX) ? *(const f32x4*)(ctx + (b << 7) + c)
                            : *(const f32x4*)(x   + (b << 7) + (c - CTX));
        ushort4 o;
        o.x = f2bf(v[0]); o.y = f2bf(v[1]); o.z = f2bf(v[2]); o.w = f2bf(v[3]);
        *(ushort4*)(xcat + idx4) = o;
    } else if (blk < 5120) {                 // wcat: HDIM x KCAT, rows sorted
        int idx = (blk - 4096) * 256 + tid;
        int p = idx >> 8, c = idx & 255;
        int h = h_of(p);
        float v;
        if (c < CTX) v = ctx_w[(h << 7) + c];
        else {
            int col = c - CTX;               // mask0: dpos(p) >= col
            v = (dpos_dev(p) >= col) ? w0[(h << 7) + col] : 0.0f;
        }
        wcat[idx] = f2bf(v);
    } else if (blk < 6144) {                 // w1m: one dest row per block
        const int po = blk - 5120;
        const int drow = dpos_dev(po);
        const float* src = w1 + (size_t)h_of(po) * HDIM;
        *((f32x4*)srow + tid) = *((const f32x4*)src + tid);   // 1024 floats
        __syncthreads();
        ushort4 o;
#pragma unroll
        for (int e = 0; e < 4; ++e) {
            int pi = 4 * tid + e;
            float v = (drow >= dpos_dev(pi)) ? srow[h_of(pi)] : 0.0f;
            ((uint16_t*)&o)[e] = f2bf(v);
        }
        *((ushort4*)(w1m + (size_t)po * HDIM) + tid) = o;
    } else if (blk < 9216) {                 // w2p: one dest row per block
        const int oo = blk - 6144;           // 0..3071
        const int g = oo / OUT_PAD, t = oo - g * OUT_PAD;
        const bool live = (t < OUT_MULT);    // block-uniform branch
        if (live) {
            const float* src = w2 + (size_t)(g * OUT_MULT + t) * HDIM;
            *((f32x4*)srow + tid) = *((const f32x4*)src + tid);
        }
        __syncthreads();
        ushort4 o;
#pragma unroll
        for (int e = 0; e < 4; ++e) {
            int pi = 4 * tid + e;
            float v = (live && g > dpos_dev(pi)) ? srow[h_of(pi)] : 0.0f;
            ((uint16_t*)&o)[e] = f2bf(v);
        }
        *((ushort4*)(w2p + (size_t)oo * HDIM) + tid) = o;
    } else if (blk < 9232) {                 // biases
        int idx = (blk - 9216) * 256 + tid;  // 0..4095
        if (idx < HDIM) {
            int h = h_of(idx);
            b0p[idx] = b0[h];
            b1p[idx] = b1[h];
        } else {
            int oo = idx - HDIM;             // 0..3071
            int g = oo / OUT_PAD, t = oo - g * OUT_PAD;
            b2p[oo] = (t < OUT_MULT) ? b2[g * OUT_MULT + t] : 0.0f;
        }
    } else {                                 // zero ldsum (BATCH floats)
        int idx = (blk - 9232) * 256 + tid;
        ldz[idx] = 0.0f;
    }
}

// ---------------- bf16 GEMM body, C = A @ B^T + bias (relu, bf16 out) -------
// BK=64, XOR-swizzled LDS (conflict-free ds_read_b128), K prefix by MODE.
// nt flipped (NT-1-..): heavy-K tiles launch first -> shorter straggler tail.

template<int MODE>
__device__ __forceinline__ void gemm_bt_body(
    const uint16_t* __restrict__ A,
    const uint16_t* __restrict__ B,
    const float*    __restrict__ bias,
    uint16_t*       __restrict__ C,
    int N, int K, int NT)
{
    __shared__ __align__(16) uint16_t sA[128 * 64];   // 16 KB
    __shared__ __align__(16) uint16_t sB[128 * 64];   // 16 KB

    const int GM    = 64;
    const int per   = GM * NT;
    const int id    = blockIdx.x;
    const int grp   = id / per;
    const int rem   = id - grp * per;
    const int mt    = grp * GM + (rem & (GM - 1));
    const int nt    = (NT - 1) - (rem >> 6);          // heavy tiles first
    const int bm    = mt << 7;
    const int bn    = nt << 7;

    int K_eff;
    if (MODE == 0)      { int dmax = dpos_dev(bn + 127); K_eff = 128 + dmax + 1; }
    else                { int dmax = dpos_dev(bn + 127); K_eff = kpref_dev(dmax + 1); }
    K_eff = min(K, (K_eff + 63) & ~63);

    const int tid   = threadIdx.x;
    const int wid   = tid >> 6;
    const int lane  = tid & 63;
    const int wm    = (wid & 1) << 6;
    const int wn    = (wid >> 1) << 6;
    const int lrow  = lane & 15;
    const int lquad = lane >> 4;

    const f32x4 vzero = {0.0f, 0.0f, 0.0f, 0.0f};
    f32x4 acc[4][4];
#pragma unroll
    for (int i = 0; i < 4; ++i)
#pragma unroll
        for (int j = 0; j < 4; ++j) acc[i][j] = vzero;

    int goff[4];
#pragma unroll
    for (int t = 0; t < 4; ++t) {
        int c = t * 256 + tid;
        int row = c >> 3, j = c & 7;
        int oct = j ^ (row & 7);
        goff[t] = row * K * 2 + oct * 16;    // bytes
    }
    const char* gA = (const char*)(A + (size_t)bm * K);
    const char* gB = (const char*)(B + (size_t)bn * K);

    const int octx = lrow & 7;
    const uint16_t* rA = sA + (wm + lrow) * 64;
    const uint16_t* rB = sB + (wn + lrow) * 64;

    for (int k0 = 0; k0 < K_eff; k0 += 64) {
        __syncthreads();
        const int kb = k0 * 2;
#pragma unroll
        for (int t = 0; t < 4; ++t) {
            const int ldsoff = (t * 256 + (wid << 6)) * 16;   // wave-uniform
            async_ld16(gA + goff[t] + kb, (const char*)sA + ldsoff);
            async_ld16(gB + goff[t] + kb, (const char*)sB + ldsoff);
        }
        __syncthreads();

#pragma unroll
        for (int ks = 0; ks < 2; ++ks) {
            const int oct = ((ks << 2) | lquad) ^ octx;
            bf16x8 af[4], bfr[4];
#pragma unroll
            for (int i = 0; i < 4; ++i) af[i]  = *(const bf16x8*)(rA + i * 1024 + oct * 8);
#pragma unroll
            for (int j = 0; j < 4; ++j) bfr[j] = *(const bf16x8*)(rB + j * 1024 + oct * 8);
#pragma unroll
            for (int i = 0; i < 4; ++i)
#pragma unroll
                for (int j = 0; j < 4; ++j)
                    acc[i][j] = __builtin_amdgcn_mfma_f32_16x16x32_bf16(
                                    af[i], bfr[j], acc[i][j], 0, 0, 0);
        }
    }

#pragma unroll
    for (int j = 0; j < 4; ++j) {
        const int col = bn + wn + j * 16 + lrow;
        const float bv = bias[col];
#pragma unroll
        for (int i = 0; i < 4; ++i) {
            const int row0 = bm + wm + i * 16 + (lquad << 2);
#pragma unroll
            for (int r = 0; r < 4; ++r) {
                float v = fmaxf(acc[i][j][r] + bv, 0.0f);
                C[(size_t)(row0 + r) * N + col] = f2bf(v);
            }
        }
    }
}

// distinct names so rocprof shows each dispatch separately
__global__ __launch_bounds__(256, 2) void gemm1_k(
    const uint16_t* __restrict__ A, const uint16_t* __restrict__ B,
    const float* __restrict__ bias, uint16_t* __restrict__ C,
    int N, int K, int NT)
{ gemm_bt_body<0>(A, B, bias, C, N, K, NT); }

__global__ __launch_bounds__(256, 2) void gemm2_k(
    const uint16_t* __restrict__ A, const uint16_t* __restrict__ B,
    const float* __restrict__ bias, uint16_t* __restrict__ C,
    int N, int K, int NT)
{ gemm_bt_body<1>(A, B, bias, C, N, K, NT); }

// ---------------- spline evaluation (VERBATIM known-good math) --------------
// NOTE: the trans-op diet (Taylor softmax exp + fused log) failed absmax=0.75
// in R7/R8 despite airtight algebra -- unresolved. Do NOT touch this math.

__device__ __forceinline__ float frcp(float v) { return __builtin_amdgcn_rcpf(v); }
__device__ __forceinline__ float softplusf(float v) {
    return fmaxf(v, 0.0f) + __logf(1.0f + __expf(-fabsf(v)));
}

__device__ __forceinline__ void spline_eval(const float* __restrict__ pp,
                                            float xv, float& yout, float& ldout)
{
    float p[OUT_MULT];
#pragma unroll
    for (int k = 0; k < OUT_MULT; ++k) p[k] = pp[k];

    const float TAILF = 3.0f;
    const float MIN_W = 0.001f, MIN_H = 0.001f, MIN_D = 0.001f;
    const float INV_SCALE = 1.0f / 724.0773439350246f;   // 1/sqrt(H*H/2)

    const float xc = fminf(fmaxf(xv, -TAILF), TAILF);

    float uw[NB], uh[NB];
#pragma unroll
    for (int k = 0; k < NB; ++k) { uw[k] = p[k] * INV_SCALE; uh[k] = p[NB + k] * INV_SCALE; }
    float mw = uw[0], mh = uh[0];
#pragma unroll
    for (int k = 1; k < NB; ++k) { mw = fmaxf(mw, uw[k]); mh = fmaxf(mh, uh[k]); }
    float ew[NB], eh[NB], sw = 0.0f, sh = 0.0f;
#pragma unroll
    for (int k = 0; k < NB; ++k) {
        ew[k] = __expf(uw[k] - mw); sw += ew[k];
        eh[k] = __expf(uh[k] - mh); sh += eh[k];
    }
    const float FACW = (1.0f - MIN_W * NB) * frcp(sw);
    const float FACH = (1.0f - MIN_H * NB) * frcp(sh);

    float cw[NB + 1], ch[NB + 1];
    cw[0] = -TAILF; ch[0] = -TAILF;
    float aw = 0.0f, ah = 0.0f;
#pragma unroll
    for (int k = 0; k < NB; ++k) {
        aw += MIN_W + FACW * ew[k];
        ah += MIN_H + FACH * eh[k];
        cw[k + 1] = (k == NB - 1) ? TAILF : 2.0f * TAILF * aw - TAILF;
        ch[k + 1] = (k == NB - 1) ? TAILF : 2.0f * TAILF * ah - TAILF;
    }

    float dd[NB + 1];
    dd[0]  = 1.0f;   // MIN_D + softplus(DPAD) == 1 exactly by construction
    dd[NB] = 1.0f;
#pragma unroll
    for (int k = 1; k < NB; ++k) dd[k] = MIN_D + softplusf(p[2 * NB + (k - 1)]);

    float in_cw = cw[0], cw_n = cw[1], in_ch = ch[0], ch_n = ch[1];
    float d0 = dd[0], d1 = dd[1];
#pragma unroll
    for (int k = 1; k < NB; ++k) {
        const bool ge = (xc >= cw[k]);
        in_cw = ge ? cw[k]     : in_cw;
        cw_n  = ge ? cw[k + 1] : cw_n;
        in_ch = ge ? ch[k]     : in_ch;
        ch_n  = ge ? ch[k + 1] : ch_n;
        d0    = ge ? dd[k]     : d0;
        d1    = ge ? dd[k + 1] : d1;
    }
    const float in_w  = cw_n - in_cw;
    const float in_h  = ch_n - in_ch;
    const float inv_w = frcp(in_w);
    const float delta = in_h * inv_w;
    const float theta = (xc - in_cw) * inv_w;
    const float omt   = 1.0f - theta;
    const float t1m   = theta * omt;
    const float denom = delta + (d0 + d1 - 2.0f * delta) * t1m;
    const float num   = in_h * (delta * theta * theta + d0 * t1m);
    float yv = in_ch + num * frcp(denom);
    float ld = 2.0f * __logf(delta)
             + __logf(d1 * theta * theta + 2.0f * delta * t1m + d0 * omt * omt)
             - 2.0f * __logf(denom);
    const bool inside = fabsf(xv) <= TAILF;
    yout  = inside ? yv : xv;
    ldout = inside ? ld : 0.0f;
}

// ---------------- fused GEMM3 + spline --------------------------------------
// Block tile: 128 M x 96 N (= 4 complete padded groups). Waves 2x2: 64 x 48.
// BK=64 + XOR-swizzled LDS. K prefix: kpref(4*nt+3) rounded to 64
// (zero-weight tail -> bit-identical). nt flipped: heavy tiles first.
// Single-phase epilogue: 128 x stride-100 f32 ep tile (51.2 KB alias).

__global__ __launch_bounds__(256, 2) void gemm3_spline(
    const uint16_t* __restrict__ A,      // h2: BATCH x HDIM (sorted K)
    const uint16_t* __restrict__ B,      // w2p: NOUTP x HDIM
    const float*    __restrict__ bias,   // b2p: NOUTP
    const float*    __restrict__ x,      // BATCH x N_IN
    float* __restrict__ y,
    float* __restrict__ ldsum)
{
    __shared__ __align__(16) char smem[128 * 100 * 4];   // 51200 B
    uint16_t* sA = (uint16_t*)smem;                 // 128*64*2 = 16384
    uint16_t* sB = (uint16_t*)(smem + 16384);       //  96*64*2 = 12288
    float* ep    = (float*)smem;                    // 128*100*4 (alias, full)

    const int NT  = 32;
    const int per = 64 * NT;                        // 2048
    const int id  = blockIdx.x;
    const int grp = id / per;
    const int rem = id - grp * per;
    const int mt  = grp * 64 + (rem & 63);
    const int nt  = 31 - (rem >> 6);                // heavy tiles first
    const int bm  = mt << 7;
    const int bn  = nt * 96;

    const int K = HDIM;
    int K_eff = kpref_dev(4 * nt + 3);
    K_eff = min(K, (K_eff + 63) & ~63);

    const int tid   = threadIdx.x;
    const int wid   = tid >> 6;
    const int lane  = tid & 63;
    const int wm    = (wid & 1) << 6;
    const int wn    = (wid >> 1) * 48;
    const int lrow  = lane & 15;
    const int lquad = lane >> 4;

    const f32x4 vzero = {0.0f, 0.0f, 0.0f, 0.0f};
    f32x4 acc[4][3];
#pragma unroll
    for (int i = 0; i < 4; ++i)
#pragma unroll
        for (int j = 0; j < 3; ++j) acc[i][j] = vzero;

    int goffA[4], goffB[3];
#pragma unroll
    for (int t = 0; t < 4; ++t) {
        int c = t * 256 + tid;
        int row = c >> 3, j = c & 7;
        goffA[t] = row * K * 2 + (j ^ (row & 7)) * 16;
    }
#pragma unroll
    for (int t = 0; t < 3; ++t) {
        int c = t * 256 + tid;
        int row = c >> 3, j = c & 7;
        goffB[t] = row * K * 2 + (j ^ (row & 7)) * 16;
    }
    const char* gA = (const char*)(A + (size_t)bm * K);
    const char* gB = (const char*)(B + (size_t)bn * K);

    const int octx = lrow & 7;
    const uint16_t* rA = sA + (wm + lrow) * 64;
    const uint16_t* rB = sB + (wn + lrow) * 64;

    for (int k0 = 0; k0 < K_eff; k0 += 64) {
        __syncthreads();
        const int kb = k0 * 2;
#pragma unroll
        for (int t = 0; t < 4; ++t) {
            const int ldsoff = (t * 256 + (wid << 6)) * 16;
            async_ld16(gA + goffA[t] + kb, (const char*)sA + ldsoff);
            if (t < 3)
                async_ld16(gB + goffB[t] + kb, (const char*)sB + ldsoff);
        }
        __syncthreads();

#pragma unroll
        for (int ks = 0; ks < 2; ++ks) {
            const int oct = ((ks << 2) | lquad) ^ octx;
            bf16x8 af[4], bfr[3];
#pragma unroll
            for (int i = 0; i < 4; ++i) af[i]  = *(const bf16x8*)(rA + i * 1024 + oct * 8);
#pragma unroll
            for (int j = 0; j < 3; ++j) bfr[j] = *(const bf16x8*)(rB + j * 1024 + oct * 8);
#pragma unroll
            for (int i = 0; i < 4; ++i)
#pragma unroll
                for (int j = 0; j < 3; ++j)
                    acc[i][j] = __builtin_amdgcn_mfma_f32_16x16x32_bf16(
                                    af[i], bfr[j], acc[i][j], 0, 0, 0);
        }
    }

    __syncthreads();                    // staging consumers done; reuse as ep
#pragma unroll
    for (int j = 0; j < 3; ++j) {
        const int col = wn + j * 16 + lrow;
        const float bv = bias[bn + col];
#pragma unroll
        for (int i = 0; i < 4; ++i) {
            const int r0 = wm + i * 16 + (lquad << 2);
#pragma unroll
            for (int r = 0; r < 4; ++r)
                ep[(r0 + r) * 100 + col] = acc[i][j][r] + bv;
        }
    }
    __syncthreads();

    // 512 spline evals: thread handles elements tid and tid+256
#pragma unroll
    for (int e = 0; e < 2; ++e) {
        const int idx  = tid + (e << 8);
        const int row  = idx >> 2;          // 0..127
        const int sg   = idx & 3;           // group within tile
        const int grow = bm + row;
        const float xv = x[(size_t)grow * N_IN + (4 * nt + sg)];
        float yv, ld;
        spline_eval(ep + row * 100 + sg * OUT_PAD, xv, yv, ld);
        y[(size_t)grow * N_IN + 4 * nt + sg] = yv;

        // sum ld over the 4 lanes of the quad (same row)
        ld += __shfl_xor(ld, 1, 64);
        ld += __shfl_xor(ld, 2, 64);
        if (sg == 0) atomicAdd(&ldsum[grow], ld);
    }
}

// ---------------- host orchestration ----------------------------------------

extern "C" void kernel_launch(void* const* d_in, const int* in_sizes, int n_in,
                              void* d_out, int out_size, void* d_ws, size_t ws_size,
                              hipStream_t stream)
{
    const float* x     = (const float*)d_in[0];
    const float* ctx   = (const float*)d_in[1];
    const float* ctx_w = (const float*)d_in[2];
    const float* w0    = (const float*)d_in[3];
    const float* b0    = (const float*)d_in[4];
    const float* w1    = (const float*)d_in[5];
    const float* b1    = (const float*)d_in[6];
    const float* w2    = (const float*)d_in[7];
    const float* b2    = (const float*)d_in[8];
    // d_in[9..11] = masks: unused (computed analytically from indices)

    char* ws = (char*)d_ws;
    const size_t XCAT_B = (size_t)BATCH * KCAT * 2;   //   8 MB
    const size_t H_B    = (size_t)BATCH * HDIM * 2;   //  32 MB each
    const size_t WCAT_B = (size_t)HDIM * KCAT * 2;
    const size_t W1_B   = (size_t)HDIM * HDIM * 2;
    const size_t W2P_B  = (size_t)NOUTP * HDIM * 2;

    uint16_t* xcat = (uint16_t*)(ws);
    uint16_t* h1   = (uint16_t*)(ws + XCAT_B);
    uint16_t* h2   = (uint16_t*)(ws + XCAT_B + H_B);
    uint16_t* wcat = (uint16_t*)(ws + XCAT_B + 2 * H_B);
    uint16_t* w1m  = (uint16_t*)(ws + XCAT_B + 2 * H_B + WCAT_B);
    uint16_t* w2p  = (uint16_t*)(ws + XCAT_B + 2 * H_B + WCAT_B + W1_B);
    float*    b0p  = (float*)   (ws + XCAT_B + 2 * H_B + WCAT_B + W1_B + W2P_B);
    float*    b1p  = b0p + HDIM;
    float*    b2p  = b1p + HDIM;

    float* yout  = (float*)d_out;
    float* ldout = yout + (size_t)BATCH * N_IN;

    pack_all<<<9296, 256, 0, stream>>>(x, ctx, ctx_w, w0, b0, w1, b1, w2, b2,
                                       xcat, wcat, w1m, w2p, b0p, b1p, b2p,
                                       ldout);

    const dim3 blk(256);
    gemm1_k<<<dim3(128 * (HDIM / 128)), blk, 0, stream>>>(
        xcat, wcat, b0p, h1, HDIM, KCAT, HDIM / 128);
    gemm2_k<<<dim3(128 * (HDIM / 128)), blk, 0, stream>>>(
        h1, w1m, b1p, h2, HDIM, HDIM, HDIM / 128);
    gemm3_spline<<<dim3(128 * 32), blk, 0, stream>>>(
        h2, w2p, b2p, x, yout, ldout);
}